// Round 5
// baseline (6960.022 us; speedup 1.0000x reference)
//
#include <hip/hip_runtime.h>
#include <hip/hip_fp16.h>
#include <math.h>

#define B_    512
#define T_    75
#define IN_   768
#define H_    256
#define NSPAN 8
#define OUTD  2
#define NDAYS 10
#define EPS_  1e-5f
#define MAXN_ 0.999f
#define CLIP_ (1.0f - 1e-7f)

// ---------------- wave helpers (wave = 64 lanes) ----------------
__device__ __forceinline__ float wred(float v) {
#pragma unroll
    for (int o = 32; o > 0; o >>= 1) v += __shfl_xor(v, o, 64);
    return v;
}
__device__ __forceinline__ float artanh_(float x) {        // libm version (prep kernels)
    x = fminf(x, CLIP_);
    return 0.5f * logf((1.f + x) / (1.f - x));
}
__device__ __forceinline__ float sigm_(float x) { return 1.f / (1.f + expf(-x)); }
__device__ __forceinline__ float h2f_(unsigned short u) {
    union { unsigned short us; __half h; } cv; cv.us = u;
    return __half2float(cv.h);
}
// ---- fast-math versions (encoder hot path). Args are wave-uniform norms >= 0. ----
__device__ __forceinline__ float frcp_(float x) { return __builtin_amdgcn_rcpf(x); }
__device__ __forceinline__ float tanh_f(float x) {         // x >= 0
    if (x < 0.01f) return x * (1.f - 0.33333334f * x * x); // uniform branch
    return 1.f - 2.f * frcp_(__expf(2.f * x) + 1.f);
}
__device__ __forceinline__ float artanh_f(float x) {       // 0 <= x < 1
    x = fminf(x, CLIP_);
    if (x < 0.01f) return x * (1.f + 0.33333334f * x * x);
    return 0.5f * __logf((1.f + x) * frcp_(1.f - x));
}

// -------- register-array mobius primitives (one wave owns a 256-vector, 4/lane) --------
__device__ __forceinline__ float rnorm4(const float* v) {
    float ss = 0.f;
#pragma unroll
    for (int q = 0; q < 4; ++q) ss = fmaf(v[q], v[q], ss);
    ss = wred(ss);
    return sqrtf(fmaxf(ss, 1e-15f));
}
__device__ __forceinline__ void mv_finish_reg(float* v, float xn) {
    float n = fmaxf(rnorm4(v), EPS_);
    float tt = tanh_f(n * frcp_(xn) * artanh_f(xn));
    float sc = tt * frcp_(n);
    if (tt > MAXN_) sc = MAXN_ * frcp_(n);
#pragma unroll
    for (int q = 0; q < 4; ++q) v[q] *= sc;
}
__device__ __forceinline__ void madd_reg(float* x, const float* y) {
    float x2 = 0.f, y2 = 0.f, xy = 0.f;
#pragma unroll
    for (int q = 0; q < 4; ++q) {
        x2 = fmaf(x[q], x[q], x2);
        y2 = fmaf(y[q], y[q], y2);
        xy = fmaf(x[q], y[q], xy);
    }
    x2 = wred(x2); y2 = wred(y2); xy = wred(xy);
    float den = fmaxf(1.f + 2.f * xy + x2 * y2, EPS_);
    float cx = 1.f + 2.f * xy + y2, cy = 1.f - x2;
    float nn = 0.f;
#pragma unroll
    for (int q = 0; q < 4; ++q) {
        float nv = cx * x[q] + cy * y[q];
        x[q] = nv;
        nn = fmaf(nv, nv, nn);
    }
    nn = wred(nn);
    float s = frcp_(den);
    float pn = sqrtf(fmaxf(nn, 1e-15f)) * s;
    if (pn > MAXN_) s *= MAXN_ * frcp_(pn);
#pragma unroll
    for (int q = 0; q < 4; ++q) x[q] *= s;
}
__device__ __forceinline__ void lsig_reg(float* v) {
    float n = fmaxf(rnorm4(v), EPS_);
    float s = artanh_f(n) * frcp_(n);
#pragma unroll
    for (int q = 0; q < 4; ++q) v[q] = frcp_(1.f + __expf(-v[q] * s));
}
__device__ __forceinline__ void pmul_reg(const float* w, const float* x, float* o, float* onorm) {
    float xn = fmaxf(rnorm4(x), EPS_);
#pragma unroll
    for (int q = 0; q < 4; ++q) o[q] = w[q] * x[q];
    float wxn = fmaxf(rnorm4(o), EPS_);
    float tt = tanh_f(wxn * frcp_(xn) * artanh_f(xn));
    float sc = tt * frcp_(wxn);
    float nrm = tt;
    if (tt > MAXN_) { sc = MAXN_ * frcp_(wxn); nrm = MAXN_; }
#pragma unroll
    for (int q = 0; q < 4; ++q) o[q] *= sc;
    if (onorm) *onorm = fmaxf(nrm, EPS_);
}

// ---------------- prep kernels ----------------
__global__ __launch_bounds__(256) void k_bias(const float* __restrict__ eb, float* __restrict__ bv) {
    int wid = threadIdx.x >> 6, lane = threadIdx.x & 63;
    if (wid >= 3) return;
    const float* p = eb + wid * H_;
    float v0 = p[lane], v1 = p[lane + 64], v2 = p[lane + 128], v3 = p[lane + 192];
    float ss = wred(v0 * v0 + v1 * v1 + v2 * v2 + v3 * v3);
    float n = sqrtf(fmaxf(ss, 1e-15f));
    float nc = fmaxf(n, EPS_);
    float s = tanhf(nc) / nc;
    float nv = n * s;
    if (nv > MAXN_) s *= MAXN_ / nv;
    bv[wid * H_ + lane] = v0 * s;
    bv[wid * H_ + lane + 64] = v1 * s;
    bv[wid * H_ + lane + 128] = v2 * s;
    bv[wid * H_ + lane + 192] = v3 * s;
}

// WTh[k][j] = f16(enc_w_hh[j][k])  (256 x 768, half precision)
__global__ __launch_bounds__(256) void k_transpose(const float* __restrict__ W, unsigned short* __restrict__ WTh) {
    int k = blockIdx.x; // 0..255
    for (int j = threadIdx.x; j < 768; j += 256) {
        __half h = __float2half(W[(size_t)j * 256 + k]);
        union { __half h; unsigned short us; } cv; cv.h = h;
        WTh[(size_t)k * 768 + j] = cv.us;
    }
}

__global__ __launch_bounds__(256) void k_row_scale(const float* __restrict__ x, float* __restrict__ xs, float* __restrict__ xn) {
    int wid = threadIdx.x >> 6, lane = threadIdx.x & 63;
    int row = blockIdx.x * 4 + wid;
    const float* p = x + (size_t)row * IN_;
    float ss = 0.f;
#pragma unroll
    for (int q = 0; q < 12; ++q) { float v = p[lane + 64 * q]; ss = fmaf(v, v, ss); }
    ss = wred(ss);
    float n = sqrtf(fmaxf(ss, 1e-15f));
    float nc = fmaxf(n, EPS_);
    float s = tanhf(nc) / nc;
    float nv = n * s;
    if (nv > MAXN_) s *= MAXN_ / nv;
    if (lane == 0) { xs[row] = s; xn[row] = fmaxf(n * s, EPS_); }
}

__global__ __launch_bounds__(256) void k_ux_scale(float* __restrict__ MX, const float* __restrict__ xs, const float* __restrict__ xnb) {
    int wid = threadIdx.x >> 6, lane = threadIdx.x & 63;
    int rg = blockIdx.x * 4 + wid;
    int row = rg / 3, g = rg - row * 3;
    float s = xs[row], xv = xnb[row];
    float* p = MX + (size_t)row * IN_ + g * H_;
    float v0 = p[lane] * s, v1 = p[lane + 64] * s, v2 = p[lane + 128] * s, v3 = p[lane + 192] * s;
    float ss = wred(v0 * v0 + v1 * v1 + v2 * v2 + v3 * v3);
    float mxn = fmaxf(sqrtf(fmaxf(ss, 1e-15f)), EPS_);
    float tt = tanhf(mxn / xv * artanh_(xv));
    float sc = tt / mxn;
    if (tt > MAXN_) sc = MAXN_ / mxn;
    p[lane] = v0 * sc; p[lane + 64] = v1 * sc; p[lane + 128] = v2 * sc; p[lane + 192] = v3 * sc;
}

// ---------------- generic f32 GEMM (128x128 tile): C = A @ B^T (+bias)(+relu) ----------------
#define BM 128
#define BN 128
#define BKK 16
__global__ __launch_bounds__(256) void k_gemm_bt(
    const float* __restrict__ A, int lda,
    const float* __restrict__ Bm,
    const float* __restrict__ bias,
    float* __restrict__ C,
    int N, int K, int act)
{
    __shared__ float As[BKK][BM + 4];
    __shared__ float Bs[BKK][BN + 4];
    int tid = threadIdx.x;
    int m0 = blockIdx.y * BM, n0 = blockIdx.x * BN;
    int lr = tid >> 2;
    int lc = (tid & 3) << 2;
    int row0 = (tid >> 4) << 3;
    int col0 = (tid & 15) << 3;
    float acc[8][8];
#pragma unroll
    for (int i = 0; i < 8; ++i)
#pragma unroll
        for (int j = 0; j < 8; ++j) acc[i][j] = 0.f;

    for (int k0 = 0; k0 < K; k0 += BKK) {
        float4 a0 = *(const float4*)&A[(size_t)(m0 + lr) * lda + k0 + lc];
        float4 a1 = *(const float4*)&A[(size_t)(m0 + lr + 64) * lda + k0 + lc];
        float4 b0 = *(const float4*)&Bm[(size_t)(n0 + lr) * K + k0 + lc];
        float4 b1 = *(const float4*)&Bm[(size_t)(n0 + lr + 64) * K + k0 + lc];
        __syncthreads();
        As[lc + 0][lr] = a0.x; As[lc + 1][lr] = a0.y; As[lc + 2][lr] = a0.z; As[lc + 3][lr] = a0.w;
        As[lc + 0][lr + 64] = a1.x; As[lc + 1][lr + 64] = a1.y; As[lc + 2][lr + 64] = a1.z; As[lc + 3][lr + 64] = a1.w;
        Bs[lc + 0][lr] = b0.x; Bs[lc + 1][lr] = b0.y; Bs[lc + 2][lr] = b0.z; Bs[lc + 3][lr] = b0.w;
        Bs[lc + 0][lr + 64] = b1.x; Bs[lc + 1][lr + 64] = b1.y; Bs[lc + 2][lr + 64] = b1.z; Bs[lc + 3][lr + 64] = b1.w;
        __syncthreads();
#pragma unroll
        for (int k = 0; k < BKK; ++k) {
            float4 x0 = *(const float4*)&As[k][row0];
            float4 x1 = *(const float4*)&As[k][row0 + 4];
            float4 y0 = *(const float4*)&Bs[k][col0];
            float4 y1 = *(const float4*)&Bs[k][col0 + 4];
            float xa[8] = {x0.x, x0.y, x0.z, x0.w, x1.x, x1.y, x1.z, x1.w};
            float yb[8] = {y0.x, y0.y, y0.z, y0.w, y1.x, y1.y, y1.z, y1.w};
#pragma unroll
            for (int i = 0; i < 8; ++i)
#pragma unroll
                for (int j = 0; j < 8; ++j) acc[i][j] = fmaf(xa[i], yb[j], acc[i][j]);
        }
    }
    float bvv[8];
#pragma unroll
    for (int j = 0; j < 8; ++j) bvv[j] = bias ? bias[n0 + col0 + j] : 0.f;
#pragma unroll
    for (int i = 0; i < 8; ++i) {
        float vv[8];
#pragma unroll
        for (int j = 0; j < 8; ++j) {
            float v = acc[i][j] + bvv[j];
            vv[j] = act ? fmaxf(v, 0.f) : v;
        }
        size_t base = (size_t)(m0 + row0 + i) * N + n0 + col0;
        *(float4*)&C[base] = make_float4(vv[0], vv[1], vv[2], vv[3]);
        *(float4*)&C[base + 4] = make_float4(vv[4], vv[5], vv[6], vv[7]);
    }
}

// ---------------- small-tile f32 GEMM (64x64, BK=32, 256 thr) for M=512 layers ----------------
__global__ __launch_bounds__(256) void k_gemm_bt64(
    const float* __restrict__ A, int lda,
    const float* __restrict__ Bm,
    const float* __restrict__ bias,
    float* __restrict__ C,
    int N, int K, int act)
{
    __shared__ float As[32][64 + 4];
    __shared__ float Bs[32][64 + 4];
    int tid = threadIdx.x;
    int m0 = blockIdx.y * 64, n0 = blockIdx.x * 64;
    int lr = tid >> 2;            // 0..63
    int lc = (tid & 3) << 3;      // 0,8,16,24
    int row0 = (tid >> 4) << 2;   // 0..60
    int col0 = (tid & 15) << 2;   // 0..60
    float acc[4][4];
#pragma unroll
    for (int i = 0; i < 4; ++i)
#pragma unroll
        for (int j = 0; j < 4; ++j) acc[i][j] = 0.f;

    for (int k0 = 0; k0 < K; k0 += 32) {
        float4 a0 = *(const float4*)&A[(size_t)(m0 + lr) * lda + k0 + lc];
        float4 a1 = *(const float4*)&A[(size_t)(m0 + lr) * lda + k0 + lc + 4];
        float4 b0 = *(const float4*)&Bm[(size_t)(n0 + lr) * K + k0 + lc];
        float4 b1 = *(const float4*)&Bm[(size_t)(n0 + lr) * K + k0 + lc + 4];
        __syncthreads();
        As[lc + 0][lr] = a0.x; As[lc + 1][lr] = a0.y; As[lc + 2][lr] = a0.z; As[lc + 3][lr] = a0.w;
        As[lc + 4][lr] = a1.x; As[lc + 5][lr] = a1.y; As[lc + 6][lr] = a1.z; As[lc + 7][lr] = a1.w;
        Bs[lc + 0][lr] = b0.x; Bs[lc + 1][lr] = b0.y; Bs[lc + 2][lr] = b0.z; Bs[lc + 3][lr] = b0.w;
        Bs[lc + 4][lr] = b1.x; Bs[lc + 5][lr] = b1.y; Bs[lc + 6][lr] = b1.z; Bs[lc + 7][lr] = b1.w;
        __syncthreads();
#pragma unroll
        for (int k = 0; k < 32; ++k) {
            float4 xa = *(const float4*)&As[k][row0];
            float4 yb = *(const float4*)&Bs[k][col0];
            float xv[4] = {xa.x, xa.y, xa.z, xa.w};
            float yv[4] = {yb.x, yb.y, yb.z, yb.w};
#pragma unroll
            for (int i = 0; i < 4; ++i)
#pragma unroll
                for (int j = 0; j < 4; ++j) acc[i][j] = fmaf(xv[i], yv[j], acc[i][j]);
        }
    }
    float bvv[4];
#pragma unroll
    for (int j = 0; j < 4; ++j) bvv[j] = bias ? bias[n0 + col0 + j] : 0.f;
#pragma unroll
    for (int i = 0; i < 4; ++i) {
        float vv[4];
#pragma unroll
        for (int j = 0; j < 4; ++j) {
            float v = acc[i][j] + bvv[j];
            vv[j] = act ? fmaxf(v, 0.f) : v;
        }
        *(float4*)&C[(size_t)(m0 + row0 + i) * N + n0 + col0] = make_float4(vv[0], vv[1], vv[2], vv[3]);
    }
}

// ---------------- mobius GRU encoder v5: 1 row/block, 512 blocks, 2 blocks/CU ----------------
// Phase1: 4 cols x 64-k per thread (acc[4]); phase2: 2 cols x 64-k (acc[2]).
// Elementwise: wave 0 only; co-resident second block's matvec waves fill the SIMDs
// while this block sits in its serial phase. Fast transcendentals shorten the chain.
__global__ __launch_bounds__(512) void k_encoder(
    const float* __restrict__ UX, const unsigned short* __restrict__ WTh,
    const float* __restrict__ bv, float* __restrict__ Hfull)
{
    __shared__ float h32[256];
    __shared__ float C32[256];
    __shared__ float P_s[4][512];       // 8KB partials (phase1 cols<512, phase2 cols<256)
    __shared__ float bias_s[3][256];

    int tid = threadIdx.x;
    int wid = tid >> 6, lane = tid & 63;
    int b = blockIdx.x;

    for (int i = tid; i < 768; i += 512) bias_s[i >> 8][i & 255] = bv[i];
    for (int i = tid; i < 256; i += 512) h32[i] = 0.f;
    __syncthreads();

    // phase1 mapping: cg = tid&127 (4 cols each), ks = tid>>7 (64-k slice)
    int cg = tid & 127, ks = tid >> 7;
    int p1c0 = cg * 4;                             // 0..508 in P-col space
    int wcol1 = (p1c0 < 256) ? p1c0 : p1c0 + 256;  // r cols 0..255 / z cols 512..767
    const unsigned short* w1 = WTh + wcol1;
    // phase2 mapping: 2 cols each
    int p2c0 = cg * 2;                             // 0..254
    const unsigned short* w2 = WTh + 256 + p2c0;   // h cols 256..511
    int kbase = ks * 64;

    float hreg[4] = {0.f, 0.f, 0.f, 0.f};
    float zv[4];
    float rhn = EPS_;

    for (int t = 0; t < T_; ++t) {
        // ---- UX prefetch (wave 0 only) ----
        float uxp_r[4], uxp_h[4], uxp_z[4];
        if (wid == 0) {
            const float* uxr = UX + ((size_t)b * T_ + t) * IN_;
#pragma unroll
            for (int q = 0; q < 4; ++q) {
                uxp_r[q] = uxr[lane + 64 * q];
                uxp_h[q] = uxr[256 + lane + 64 * q];
                uxp_z[q] = uxr[512 + lane + 64 * q];
            }
        }

        // ---- phase1: raw h @ {W_hr, W_hz}^T (f16 weights) ----
        {
            float a[4] = {0.f, 0.f, 0.f, 0.f};
            for (int kk = 0; kk < 64; kk += 4) {
                int k = kbase + kk;
                float4 hv = *(const float4*)&h32[k];
#pragma unroll
                for (int i = 0; i < 4; ++i) {
                    ushort4 wu = *(const ushort4*)&w1[(size_t)(k + i) * 768];
                    float e = ((const float*)&hv)[i];
                    a[0] = fmaf(e, h2f_(wu.x), a[0]);
                    a[1] = fmaf(e, h2f_(wu.y), a[1]);
                    a[2] = fmaf(e, h2f_(wu.z), a[2]);
                    a[3] = fmaf(e, h2f_(wu.w), a[3]);
                }
            }
            *(float4*)&P_s[ks][p1c0] = make_float4(a[0], a[1], a[2], a[3]);
        }
        __syncthreads();

        // ---- elementwise 1 (wave 0) ----
        if (wid == 0) {
            float zr[4], rr[4], tmp[4];
#pragma unroll
            for (int q = 0; q < 4; ++q) {
                int j = lane + 64 * q;
                float sr = 0.f, sz = 0.f;
#pragma unroll
                for (int s = 0; s < 4; ++s) {
                    sr += P_s[s][j];
                    sz += P_s[s][256 + j];
                }
                rr[q] = sr; zr[q] = sz;
            }
            float hn = fmaxf(rnorm4(hreg), EPS_);
            // z gate
            mv_finish_reg(zr, hn);
            madd_reg(zr, uxp_z);
#pragma unroll
            for (int q = 0; q < 4; ++q) tmp[q] = bias_s[2][lane + 64 * q];
            madd_reg(zr, tmp);
            lsig_reg(zr);
#pragma unroll
            for (int q = 0; q < 4; ++q) zv[q] = zr[q];
            // r gate
            mv_finish_reg(rr, hn);
            madd_reg(rr, uxp_r);
#pragma unroll
            for (int q = 0; q < 4; ++q) tmp[q] = bias_s[0][lane + 64 * q];
            madd_reg(rr, tmp);
            lsig_reg(rr);
            // rh
            float rh[4];
            pmul_reg(rr, hreg, rh, &rhn);
#pragma unroll
            for (int q = 0; q < 4; ++q) C32[lane + 64 * q] = rh[q];
        }
        __syncthreads();

        // ---- phase2: raw rh @ W_hhh^T (f16 weights) ----
        {
            float c[2] = {0.f, 0.f};
            for (int kk = 0; kk < 64; kk += 4) {
                int k = kbase + kk;
                float4 cv = *(const float4*)&C32[k];
#pragma unroll
                for (int i = 0; i < 4; ++i) {
                    ushort2 wu = *(const ushort2*)&w2[(size_t)(k + i) * 768];
                    float e = ((const float*)&cv)[i];
                    c[0] = fmaf(e, h2f_(wu.x), c[0]);
                    c[1] = fmaf(e, h2f_(wu.y), c[1]);
                }
            }
            *(float2*)&P_s[ks][p2c0] = make_float2(c[0], c[1]);
        }
        __syncthreads();

        // ---- elementwise 2 (wave 0): h update ----
        if (wid == 0) {
            float ht[4], tmp[4];
#pragma unroll
            for (int q = 0; q < 4; ++q) {
                int j = lane + 64 * q;
                float sh = 0.f;
#pragma unroll
                for (int s = 0; s < 4; ++s) sh += P_s[s][j];
                ht[q] = sh;
            }
            mv_finish_reg(ht, rhn);
            madd_reg(ht, uxp_h);
#pragma unroll
            for (int q = 0; q < 4; ++q) tmp[q] = bias_s[1][lane + 64 * q];
            madd_reg(ht, tmp);                 // ht = h_tilde
            float dl[4];
#pragma unroll
            for (int q = 0; q < 4; ++q) dl[q] = -hreg[q];
            madd_reg(dl, ht);                  // delta = mobius_add(-h, h_tilde)
            float dv[4];
            pmul_reg(zv, dl, dv, nullptr);     // z (*) delta
            madd_reg(hreg, dv);                // h = mobius_add(h, ...)
            float* orow = Hfull + ((size_t)b * T_ + t) * H_;
#pragma unroll
            for (int q = 0; q < 4; ++q) {
                int j = lane + 64 * q;
                h32[j] = hreg[q];
                orow[j] = hreg[q];
            }
        }
        __syncthreads();
    }
}

// logmap0 in place over (rows, 256)
__global__ __launch_bounds__(256) void k_logmap(float* __restrict__ Y) {
    int wid = threadIdx.x >> 6, lane = threadIdx.x & 63;
    int row = blockIdx.x * 4 + wid;
    float* p = Y + (size_t)row * H_;
    float v0 = p[lane], v1 = p[lane + 64], v2 = p[lane + 128], v3 = p[lane + 192];
    float ss = wred(v0 * v0 + v1 * v1 + v2 * v2 + v3 * v3);
    float n = fmaxf(sqrtf(fmaxf(ss, 1e-15f)), EPS_);
    float s = artanh_(n) / n;
    p[lane] = v0 * s; p[lane + 64] = v1 * s; p[lane + 128] = v2 * s; p[lane + 192] = v3 * s;
}

// score[b,t] = v . tanh(S1 + b1 + q[b]) + bv, masked
__global__ __launch_bounds__(256) void k_score(
    const float* __restrict__ S1, const float* __restrict__ q,
    const float* __restrict__ b1, const float* __restrict__ av,
    const float* __restrict__ abv, const int* __restrict__ len,
    float* __restrict__ sc)
{
    int wid = threadIdx.x >> 6, lane = threadIdx.x & 63;
    int row = blockIdx.x * 4 + wid;
    int b = row / T_, t = row - b * T_;
    const float* s1 = S1 + (size_t)row * H_;
    const float* qp = q + (size_t)b * H_;
    float part = 0.f;
#pragma unroll
    for (int qq = 0; qq < 4; ++qq) {
        int j = lane + 64 * qq;
        float u = tanhf(s1[j] + b1[j] + qp[j]);
        part = fmaf(u, av[j], part);
    }
    part = wred(part) + abv[0];
    if (t >= len[b]) part = -1e9f;
    if (lane == 0) sc[row] = part;
}

// per-b: softmax over T, ctx = sum w*full, span logits + softmax -> d_out
__global__ __launch_bounds__(256) void k_ctx(
    const float* __restrict__ sc, const float* __restrict__ full,
    const float* __restrict__ spw, const float* __restrict__ spb,
    float* __restrict__ ctx, float* __restrict__ outsp)
{
    int b = blockIdx.x, tid = threadIdx.x;
    __shared__ float w_s[T_];
    __shared__ float cs[H_];
    __shared__ float red[NSPAN];
    if (tid < T_) w_s[tid] = sc[b * T_ + tid];
    __syncthreads();
    if (tid == 0) {
        float mx = -1e30f;
        for (int t = 0; t < T_; ++t) mx = fmaxf(mx, w_s[t]);
        float sum = 0.f;
        for (int t = 0; t < T_; ++t) { float e = expf(w_s[t] - mx); w_s[t] = e; sum += e; }
        float inv = 1.f / sum;
        for (int t = 0; t < T_; ++t) w_s[t] *= inv;
    }
    __syncthreads();
    float c = 0.f;
    for (int t = 0; t < T_; ++t) c = fmaf(w_s[t], full[((size_t)b * T_ + t) * H_ + tid], c);
    ctx[(size_t)b * H_ + tid] = c;
    cs[tid] = c;
    __syncthreads();
    if (tid < NSPAN) {
        float lg = spb[tid];
        for (int j = 0; j < H_; ++j) lg = fmaf(spw[tid * H_ + j], cs[j], lg);
        red[tid] = lg;
    }
    __syncthreads();
    if (tid == 0) {
        float mx = red[0];
        for (int k2 = 1; k2 < NSPAN; ++k2) mx = fmaxf(mx, red[k2]);
        float sum = 0.f;
        for (int k2 = 0; k2 < NSPAN; ++k2) sum += expf(red[k2] - mx);
        float inv = 1.f / sum;
        for (int k2 = 0; k2 < NSPAN; ++k2) outsp[(size_t)b * NSPAN + k2] = expf(red[k2] - mx) * inv;
    }
}

// Euclidean GRU cell + fc_out softmax
__global__ __launch_bounds__(256) void k_dec_cell(
    const float* __restrict__ gi, const float* __restrict__ gh,
    float* __restrict__ h, const float* __restrict__ fow,
    const float* __restrict__ fob, float* __restrict__ outp, int t)
{
    int b = blockIdx.x, j = threadIdx.x;
    __shared__ float hs[H_];
    __shared__ float red[2];
    size_t gb = (size_t)b * 768;
    float r = sigm_(gi[gb + j] + gh[gb + j]);
    float z = sigm_(gi[gb + 256 + j] + gh[gb + 256 + j]);
    float n = tanhf(fmaf(r, gh[gb + 512 + j], gi[gb + 512 + j]));
    float hv = h[(size_t)b * H_ + j];
    float hnew = (1.f - z) * n + z * hv;
    h[(size_t)b * H_ + j] = hnew;
    hs[j] = hnew;
    __syncthreads();
    int wid = j >> 6, lane = j & 63;
    if (wid < 2) {
        float p = 0.f;
#pragma unroll
        for (int q = 0; q < 4; ++q) { int c = lane + 64 * q; p = fmaf(fow[wid * H_ + c], hs[c], p); }
        p = wred(p);
        if (lane == 0) red[wid] = p + fob[wid];
    }
    __syncthreads();
    if (j == 0) {
        float l0 = red[0], l1 = red[1];
        float mx = fmaxf(l0, l1);
        float e0 = expf(l0 - mx), e1 = expf(l1 - mx);
        float inv = 1.f / (e0 + e1);
        outp[(size_t)b * (NDAYS * OUTD) + t * OUTD + 0] = e0 * inv;
        outp[(size_t)b * (NDAYS * OUTD) + t * OUTD + 1] = e1 * inv;
    }
}

extern "C" void kernel_launch(void* const* d_in, const int* in_sizes, int n_in,
                              void* d_out, int out_size, void* d_ws, size_t ws_size,
                              hipStream_t stream)
{
    (void)in_sizes; (void)n_in; (void)out_size; (void)ws_size;
    const float* x        = (const float*)d_in[0];
    const int*   len      = (const int*)  d_in[1];
    const float* enc_w_ih = (const float*)d_in[2];
    const float* enc_w_hh = (const float*)d_in[3];
    const float* enc_bias = (const float*)d_in[4];
    const float* dec_w_ih = (const float*)d_in[5];
    const float* dec_w_hh = (const float*)d_in[6];
    const float* dec_b_ih = (const float*)d_in[7];
    const float* dec_b_hh = (const float*)d_in[8];
    const float* attn_w1  = (const float*)d_in[9];
    const float* attn_b1  = (const float*)d_in[10];
    const float* attn_w2  = (const float*)d_in[11];
    const float* attn_b2  = (const float*)d_in[12];
    const float* attn_v   = (const float*)d_in[13];
    const float* attn_bv  = (const float*)d_in[14];
    const float* fc_in_w  = (const float*)d_in[15];
    const float* fc_in_b  = (const float*)d_in[16];
    const float* fc_out_w = (const float*)d_in[17];
    const float* fc_out_b = (const float*)d_in[18];
    const float* span_w   = (const float*)d_in[19];
    const float* span_b   = (const float*)d_in[20];
    float* out = (float*)d_out;
    float* wsf = (float*)d_ws;

    const size_t ROWS = (size_t)B_ * T_;            // 38400
    float* UX    = wsf;                             // 38400*768
    float* Hfull = UX + ROWS * IN_;                 // 38400*256
    float* xs    = Hfull + ROWS * H_;               // 38400
    float* xnb   = xs + ROWS;                       // 38400
    float* WT    = xnb + ROWS;                      // 256*768 floats reserved (used as f16)
    float* bvv   = WT + 256 * 768;                  // 768
    float* qbuf  = bvv + 768;                       // 512*256
    float* scb   = qbuf + (size_t)B_ * H_;          // 38400
    float* ctx   = scb + ROWS;                      // 512*256 (doubles as decoder h)
    unsigned short* WTh = (unsigned short*)WT;      // 256*768 halves
    // UX region reused after encoder/attention consume it:
    float* S1  = UX;
    float* gi  = UX;
    float* gh  = UX + (size_t)B_ * 768;
    float* inp = UX + 2 * (size_t)B_ * 768;

    k_bias<<<1, 256, 0, stream>>>(enc_bias, bvv);
    k_transpose<<<256, 256, 0, stream>>>(enc_w_hh, WTh);
    k_row_scale<<<(unsigned)(ROWS / 4), 256, 0, stream>>>(x, xs, xnb);
    k_gemm_bt<<<dim3(IN_ / BN, (unsigned)(ROWS / BM)), 256, 0, stream>>>(x, IN_, enc_w_ih, nullptr, UX, IN_, IN_, 0);
    k_ux_scale<<<(unsigned)(ROWS * 3 / 4), 256, 0, stream>>>(UX, xs, xnb);
    k_encoder<<<B_, 512, 0, stream>>>(UX, WTh, bvv, Hfull);
    k_logmap<<<(unsigned)(ROWS / 4), 256, 0, stream>>>(Hfull);
    // q = hx @ w2^T + b2   (hx rows are the t=T-1 rows of logmapped Hfull, stride T*H)
    k_gemm_bt64<<<dim3(H_ / 64, B_ / 64), 256, 0, stream>>>(Hfull + (T_ - 1) * H_, T_ * H_, attn_w2, attn_b2, qbuf, H_, H_, 0);
    k_gemm_bt<<<dim3(H_ / BN, (unsigned)(ROWS / BM)), 256, 0, stream>>>(Hfull, H_, attn_w1, nullptr, S1, H_, H_, 0);
    k_score<<<(unsigned)(ROWS / 4), 256, 0, stream>>>(S1, qbuf, attn_b1, attn_v, attn_bv, len, scb);
    k_ctx<<<B_, 256, 0, stream>>>(scb, Hfull, span_w, span_b, ctx, out);
    hipMemsetAsync(inp, 0, (size_t)B_ * 768 * sizeof(float), stream);
    for (int t = 0; t < NDAYS; ++t) {
        k_gemm_bt64<<<dim3(768 / 64, B_ / 64), 256, 0, stream>>>(inp, 768, dec_w_ih, dec_b_ih, gi, 768, 768, 0);
        k_gemm_bt64<<<dim3(768 / 64, B_ / 64), 256, 0, stream>>>(ctx, H_, dec_w_hh, dec_b_hh, gh, 768, H_, 0);
        k_dec_cell<<<B_, 256, 0, stream>>>(gi, gh, ctx, fc_out_w, fc_out_b, out + B_ * NSPAN, t);
        if (t + 1 < NDAYS)
            k_gemm_bt64<<<dim3(768 / 64, B_ / 64), 256, 0, stream>>>(ctx, H_, fc_in_w, fc_in_b, inp, 768, H_, 1);
    }
}

// Round 6
// 2163.592 us; speedup vs baseline: 3.2169x; 3.2169x over previous
//
#include <hip/hip_runtime.h>
#include <hip/hip_fp16.h>
#include <math.h>

#define B_    512
#define T_    75
#define IN_   768
#define H_    256
#define NSPAN 8
#define OUTD  2
#define NDAYS 10
#define EPS_  1e-5f
#define MAXN_ 0.999f
#define CLIP_ (1.0f - 1e-7f)

// ---------------- wave helpers (wave = 64 lanes) ----------------
__device__ __forceinline__ float wred(float v) {
#pragma unroll
    for (int o = 32; o > 0; o >>= 1) v += __shfl_xor(v, o, 64);
    return v;
}
__device__ __forceinline__ float artanh_(float x) {        // libm version (prep kernels)
    x = fminf(x, CLIP_);
    return 0.5f * logf((1.f + x) / (1.f - x));
}
__device__ __forceinline__ float sigm_(float x) { return 1.f / (1.f + expf(-x)); }
__device__ __forceinline__ float h2f_(unsigned short u) {
    union { unsigned short us; __half h; } cv; cv.us = u;
    return __half2float(cv.h);
}
__device__ __forceinline__ unsigned int packf16(float a, float b) {
    union { __half h; unsigned short us; } ca, cb;
    ca.h = __float2half(a); cb.h = __float2half(b);
    return (unsigned int)ca.us | ((unsigned int)cb.us << 16);
}
// f16-pair dot product with f32 accumulator: acc += w.x*h.x + w.y*h.y
__device__ __forceinline__ float dot2_(unsigned int w, unsigned int h, float acc) {
#if __has_builtin(__builtin_amdgcn_fdot2)
    typedef _Float16 h2_t __attribute__((ext_vector_type(2)));
    union { unsigned int u; h2_t v; } a, b;
    a.u = w; b.u = h;
    return __builtin_amdgcn_fdot2(a.v, b.v, acc, false);
#else
    float wx = h2f_((unsigned short)(w & 0xffff)), wy = h2f_((unsigned short)(w >> 16));
    float hx = h2f_((unsigned short)(h & 0xffff)), hy = h2f_((unsigned short)(h >> 16));
    return fmaf(wy, hy, fmaf(wx, hx, acc));
#endif
}
// ---- fast-math versions (encoder hot path). Args are wave-uniform norms >= 0. ----
__device__ __forceinline__ float frcp_(float x) { return __builtin_amdgcn_rcpf(x); }
__device__ __forceinline__ float tanh_f(float x) {         // x >= 0
    if (x < 0.01f) return x * (1.f - 0.33333334f * x * x); // uniform branch
    return 1.f - 2.f * frcp_(__expf(2.f * x) + 1.f);
}
__device__ __forceinline__ float artanh_f(float x) {       // 0 <= x < 1
    x = fminf(x, CLIP_);
    if (x < 0.01f) return x * (1.f + 0.33333334f * x * x);
    return 0.5f * __logf((1.f + x) * frcp_(1.f - x));
}

// -------- register-array mobius primitives (one wave owns a 256-vector, 4/lane) --------
__device__ __forceinline__ float rnorm4(const float* v) {
    float ss = 0.f;
#pragma unroll
    for (int q = 0; q < 4; ++q) ss = fmaf(v[q], v[q], ss);
    ss = wred(ss);
    return sqrtf(fmaxf(ss, 1e-15f));
}
__device__ __forceinline__ void mv_finish_reg(float* v, float xn) {
    float n = fmaxf(rnorm4(v), EPS_);
    float tt = tanh_f(n * frcp_(xn) * artanh_f(xn));
    float sc = tt * frcp_(n);
    if (tt > MAXN_) sc = MAXN_ * frcp_(n);
#pragma unroll
    for (int q = 0; q < 4; ++q) v[q] *= sc;
}
__device__ __forceinline__ void madd_reg(float* x, const float* y) {
    float x2 = 0.f, y2 = 0.f, xy = 0.f;
#pragma unroll
    for (int q = 0; q < 4; ++q) {
        x2 = fmaf(x[q], x[q], x2);
        y2 = fmaf(y[q], y[q], y2);
        xy = fmaf(x[q], y[q], xy);
    }
    x2 = wred(x2); y2 = wred(y2); xy = wred(xy);
    float den = fmaxf(1.f + 2.f * xy + x2 * y2, EPS_);
    float cx = 1.f + 2.f * xy + y2, cy = 1.f - x2;
    float nn = 0.f;
#pragma unroll
    for (int q = 0; q < 4; ++q) {
        float nv = cx * x[q] + cy * y[q];
        x[q] = nv;
        nn = fmaf(nv, nv, nn);
    }
    nn = wred(nn);
    float s = frcp_(den);
    float pn = sqrtf(fmaxf(nn, 1e-15f)) * s;
    if (pn > MAXN_) s *= MAXN_ * frcp_(pn);
#pragma unroll
    for (int q = 0; q < 4; ++q) x[q] *= s;
}
__device__ __forceinline__ void lsig_reg(float* v) {
    float n = fmaxf(rnorm4(v), EPS_);
    float s = artanh_f(n) * frcp_(n);
#pragma unroll
    for (int q = 0; q < 4; ++q) v[q] = frcp_(1.f + __expf(-v[q] * s));
}
__device__ __forceinline__ void pmul_reg(const float* w, const float* x, float* o, float* onorm) {
    float xn = fmaxf(rnorm4(x), EPS_);
#pragma unroll
    for (int q = 0; q < 4; ++q) o[q] = w[q] * x[q];
    float wxn = fmaxf(rnorm4(o), EPS_);
    float tt = tanh_f(wxn * frcp_(xn) * artanh_f(xn));
    float sc = tt * frcp_(wxn);
    float nrm = tt;
    if (tt > MAXN_) { sc = MAXN_ * frcp_(wxn); nrm = MAXN_; }
#pragma unroll
    for (int q = 0; q < 4; ++q) o[q] *= sc;
    if (onorm) *onorm = fmaxf(nrm, EPS_);
}

// ---------------- prep kernels ----------------
__global__ __launch_bounds__(256) void k_bias(const float* __restrict__ eb, float* __restrict__ bv) {
    int wid = threadIdx.x >> 6, lane = threadIdx.x & 63;
    if (wid >= 3) return;
    const float* p = eb + wid * H_;
    float v0 = p[lane], v1 = p[lane + 64], v2 = p[lane + 128], v3 = p[lane + 192];
    float ss = wred(v0 * v0 + v1 * v1 + v2 * v2 + v3 * v3);
    float n = sqrtf(fmaxf(ss, 1e-15f));
    float nc = fmaxf(n, EPS_);
    float s = tanhf(nc) / nc;
    float nv = n * s;
    if (nv > MAXN_) s *= MAXN_ / nv;
    bv[wid * H_ + lane] = v0 * s;
    bv[wid * H_ + lane + 64] = v1 * s;
    bv[wid * H_ + lane + 128] = v2 * s;
    bv[wid * H_ + lane + 192] = v3 * s;
}

// WPK[kp][j] = pack(f16(whh[j][2kp]), f16(whh[j][2kp+1]))  (128 x 768 uints)
__global__ __launch_bounds__(256) void k_packw(const float* __restrict__ whh, unsigned int* __restrict__ WPK) {
    int kp = blockIdx.x; // 0..127
    for (int j = threadIdx.x; j < 768; j += 256) {
        float w0 = whh[(size_t)j * 256 + 2 * kp];
        float w1 = whh[(size_t)j * 256 + 2 * kp + 1];
        WPK[(size_t)kp * 768 + j] = packf16(w0, w1);
    }
}

__global__ __launch_bounds__(256) void k_row_scale(const float* __restrict__ x, float* __restrict__ xs, float* __restrict__ xn) {
    int wid = threadIdx.x >> 6, lane = threadIdx.x & 63;
    int row = blockIdx.x * 4 + wid;
    const float* p = x + (size_t)row * IN_;
    float ss = 0.f;
#pragma unroll
    for (int q = 0; q < 12; ++q) { float v = p[lane + 64 * q]; ss = fmaf(v, v, ss); }
    ss = wred(ss);
    float n = sqrtf(fmaxf(ss, 1e-15f));
    float nc = fmaxf(n, EPS_);
    float s = tanhf(nc) / nc;
    float nv = n * s;
    if (nv > MAXN_) s *= MAXN_ / nv;
    if (lane == 0) { xs[row] = s; xn[row] = fmaxf(n * s, EPS_); }
}

__global__ __launch_bounds__(256) void k_ux_scale(float* __restrict__ MX, const float* __restrict__ xs, const float* __restrict__ xnb) {
    int wid = threadIdx.x >> 6, lane = threadIdx.x & 63;
    int rg = blockIdx.x * 4 + wid;
    int row = rg / 3, g = rg - row * 3;
    float s = xs[row], xv = xnb[row];
    float* p = MX + (size_t)row * IN_ + g * H_;
    float v0 = p[lane] * s, v1 = p[lane + 64] * s, v2 = p[lane + 128] * s, v3 = p[lane + 192] * s;
    float ss = wred(v0 * v0 + v1 * v1 + v2 * v2 + v3 * v3);
    float mxn = fmaxf(sqrtf(fmaxf(ss, 1e-15f)), EPS_);
    float tt = tanhf(mxn / xv * artanh_(xv));
    float sc = tt / mxn;
    if (tt > MAXN_) sc = MAXN_ / mxn;
    p[lane] = v0 * sc; p[lane + 64] = v1 * sc; p[lane + 128] = v2 * sc; p[lane + 192] = v3 * sc;
}

// ---------------- generic f32 GEMM (128x128 tile): C = A @ B^T (+bias)(+relu) ----------------
#define BM 128
#define BN 128
#define BKK 16
__global__ __launch_bounds__(256) void k_gemm_bt(
    const float* __restrict__ A, int lda,
    const float* __restrict__ Bm,
    const float* __restrict__ bias,
    float* __restrict__ C,
    int N, int K, int act)
{
    __shared__ float As[BKK][BM + 4];
    __shared__ float Bs[BKK][BN + 4];
    int tid = threadIdx.x;
    int m0 = blockIdx.y * BM, n0 = blockIdx.x * BN;
    int lr = tid >> 2;
    int lc = (tid & 3) << 2;
    int row0 = (tid >> 4) << 3;
    int col0 = (tid & 15) << 3;
    float acc[8][8];
#pragma unroll
    for (int i = 0; i < 8; ++i)
#pragma unroll
        for (int j = 0; j < 8; ++j) acc[i][j] = 0.f;

    for (int k0 = 0; k0 < K; k0 += BKK) {
        float4 a0 = *(const float4*)&A[(size_t)(m0 + lr) * lda + k0 + lc];
        float4 a1 = *(const float4*)&A[(size_t)(m0 + lr + 64) * lda + k0 + lc];
        float4 b0 = *(const float4*)&Bm[(size_t)(n0 + lr) * K + k0 + lc];
        float4 b1 = *(const float4*)&Bm[(size_t)(n0 + lr + 64) * K + k0 + lc];
        __syncthreads();
        As[lc + 0][lr] = a0.x; As[lc + 1][lr] = a0.y; As[lc + 2][lr] = a0.z; As[lc + 3][lr] = a0.w;
        As[lc + 0][lr + 64] = a1.x; As[lc + 1][lr + 64] = a1.y; As[lc + 2][lr + 64] = a1.z; As[lc + 3][lr + 64] = a1.w;
        Bs[lc + 0][lr] = b0.x; Bs[lc + 1][lr] = b0.y; Bs[lc + 2][lr] = b0.z; Bs[lc + 3][lr] = b0.w;
        Bs[lc + 0][lr + 64] = b1.x; Bs[lc + 1][lr + 64] = b1.y; Bs[lc + 2][lr + 64] = b1.z; Bs[lc + 3][lr + 64] = b1.w;
        __syncthreads();
#pragma unroll
        for (int k = 0; k < BKK; ++k) {
            float4 x0 = *(const float4*)&As[k][row0];
            float4 x1 = *(const float4*)&As[k][row0 + 4];
            float4 y0 = *(const float4*)&Bs[k][col0];
            float4 y1 = *(const float4*)&Bs[k][col0 + 4];
            float xa[8] = {x0.x, x0.y, x0.z, x0.w, x1.x, x1.y, x1.z, x1.w};
            float yb[8] = {y0.x, y0.y, y0.z, y0.w, y1.x, y1.y, y1.z, y1.w};
#pragma unroll
            for (int i = 0; i < 8; ++i)
#pragma unroll
                for (int j = 0; j < 8; ++j) acc[i][j] = fmaf(xa[i], yb[j], acc[i][j]);
        }
    }
    float bvv[8];
#pragma unroll
    for (int j = 0; j < 8; ++j) bvv[j] = bias ? bias[n0 + col0 + j] : 0.f;
#pragma unroll
    for (int i = 0; i < 8; ++i) {
        float vv[8];
#pragma unroll
        for (int j = 0; j < 8; ++j) {
            float v = acc[i][j] + bvv[j];
            vv[j] = act ? fmaxf(v, 0.f) : v;
        }
        size_t base = (size_t)(m0 + row0 + i) * N + n0 + col0;
        *(float4*)&C[base] = make_float4(vv[0], vv[1], vv[2], vv[3]);
        *(float4*)&C[base + 4] = make_float4(vv[4], vv[5], vv[6], vv[7]);
    }
}

// ---------------- small-tile f32 GEMM (64x64, BK=32, 256 thr) for M=512 layers ----------------
__global__ __launch_bounds__(256) void k_gemm_bt64(
    const float* __restrict__ A, int lda,
    const float* __restrict__ Bm,
    const float* __restrict__ bias,
    float* __restrict__ C,
    int N, int K, int act)
{
    __shared__ float As[32][64 + 4];
    __shared__ float Bs[32][64 + 4];
    int tid = threadIdx.x;
    int m0 = blockIdx.y * 64, n0 = blockIdx.x * 64;
    int lr = tid >> 2;            // 0..63
    int lc = (tid & 3) << 3;      // 0,8,16,24
    int row0 = (tid >> 4) << 2;   // 0..60
    int col0 = (tid & 15) << 2;   // 0..60
    float acc[4][4];
#pragma unroll
    for (int i = 0; i < 4; ++i)
#pragma unroll
        for (int j = 0; j < 4; ++j) acc[i][j] = 0.f;

    for (int k0 = 0; k0 < K; k0 += 32) {
        float4 a0 = *(const float4*)&A[(size_t)(m0 + lr) * lda + k0 + lc];
        float4 a1 = *(const float4*)&A[(size_t)(m0 + lr) * lda + k0 + lc + 4];
        float4 b0 = *(const float4*)&Bm[(size_t)(n0 + lr) * K + k0 + lc];
        float4 b1 = *(const float4*)&Bm[(size_t)(n0 + lr) * K + k0 + lc + 4];
        __syncthreads();
        As[lc + 0][lr] = a0.x; As[lc + 1][lr] = a0.y; As[lc + 2][lr] = a0.z; As[lc + 3][lr] = a0.w;
        As[lc + 4][lr] = a1.x; As[lc + 5][lr] = a1.y; As[lc + 6][lr] = a1.z; As[lc + 7][lr] = a1.w;
        Bs[lc + 0][lr] = b0.x; Bs[lc + 1][lr] = b0.y; Bs[lc + 2][lr] = b0.z; Bs[lc + 3][lr] = b0.w;
        Bs[lc + 4][lr] = b1.x; Bs[lc + 5][lr] = b1.y; Bs[lc + 6][lr] = b1.z; Bs[lc + 7][lr] = b1.w;
        __syncthreads();
#pragma unroll
        for (int k = 0; k < 32; ++k) {
            float4 xa = *(const float4*)&As[k][row0];
            float4 yb = *(const float4*)&Bs[k][col0];
            float xv[4] = {xa.x, xa.y, xa.z, xa.w};
            float yv[4] = {yb.x, yb.y, yb.z, yb.w};
#pragma unroll
            for (int i = 0; i < 4; ++i)
#pragma unroll
                for (int j = 0; j < 4; ++j) acc[i][j] = fmaf(xv[i], yv[j], acc[i][j]);
        }
    }
    float bvv[4];
#pragma unroll
    for (int j = 0; j < 4; ++j) bvv[j] = bias ? bias[n0 + col0 + j] : 0.f;
#pragma unroll
    for (int i = 0; i < 4; ++i) {
        float vv[4];
#pragma unroll
        for (int j = 0; j < 4; ++j) {
            float v = acc[i][j] + bvv[j];
            vv[j] = act ? fmaxf(v, 0.f) : v;
        }
        *(float4*)&C[(size_t)(m0 + row0 + i) * N + n0 + col0] = make_float4(vv[0], vv[1], vv[2], vv[3]);
    }
}

// ---------------- mobius GRU encoder v6: weights-in-registers, dot2 f16 matvec ----------------
// 256 blocks x 2 rows, 512 threads, 1 block/CU. Each thread holds one output column of the
// gate weights in VGPRs (phase1: 128 packed f16-pair uints; phase2: 64). h/rh are rounded to
// f16 pairs in LDS and broadcast-read; matvec = v_dot2_f32_f16 with f32 accumulator. No global
// weight traffic inside the 75-step loop; no k-space partial reduction.
__global__ __launch_bounds__(512) void k_encoder(
    const float* __restrict__ UX, const unsigned int* __restrict__ WPK,
    const float* __restrict__ bv, float* __restrict__ Hfull)
{
    __shared__ __align__(16) unsigned int h16u[2][128];
    __shared__ __align__(16) unsigned int c16u[2][128];
    __shared__ float P1[2][512];
    __shared__ float P2[2][2][256];
    __shared__ float bias_s[3][256];

    int tid = threadIdx.x;
    int wid = tid >> 6, lane = tid & 63;
    int b0 = blockIdx.x * 2;

    for (int i = tid; i < 768; i += 512) bias_s[i >> 8][i & 255] = bv[i];
    if (tid < 256) h16u[tid >> 7][tid & 127] = 0u;
    __syncthreads();

    // ---- one-time weight load into registers ----
    int j1 = (tid < 256) ? tid : (tid + 256);      // r cols 0..255 / z cols 512..767
    unsigned int wA[128];
#pragma unroll
    for (int kp = 0; kp < 128; ++kp) wA[kp] = WPK[(size_t)kp * 768 + j1];
    int j2i = tid & 255;                            // h gate col (256 + j2i)
    int half = tid >> 8;                            // k-half
    int kb2 = half * 64;
    unsigned int wB[64];
#pragma unroll
    for (int i = 0; i < 64; ++i) wB[i] = WPK[(size_t)(kb2 + i) * 768 + 256 + j2i];

    int row = wid;  // elementwise row (valid when wid<2)
    float hreg[4] = {0.f, 0.f, 0.f, 0.f};
    float zv[4];
    float rhn = EPS_;

    for (int t = 0; t < T_; ++t) {
        // ---- UX prefetch (waves 0,1) ----
        float uxp_r[4], uxp_h[4], uxp_z[4];
        if (wid < 2) {
            const float* uxr = UX + ((size_t)(b0 + row) * T_ + t) * IN_;
            float4 u0 = *(const float4*)&uxr[4 * lane];
            float4 u1 = *(const float4*)&uxr[256 + 4 * lane];
            float4 u2 = *(const float4*)&uxr[512 + 4 * lane];
            uxp_r[0] = u0.x; uxp_r[1] = u0.y; uxp_r[2] = u0.z; uxp_r[3] = u0.w;
            uxp_h[0] = u1.x; uxp_h[1] = u1.y; uxp_h[2] = u1.z; uxp_h[3] = u1.w;
            uxp_z[0] = u2.x; uxp_z[1] = u2.y; uxp_z[2] = u2.z; uxp_z[3] = u2.w;
        }

        // ---- phase1: h @ {W_hr, W_hz}^T  (dot2, full K per thread) ----
        {
            float a0 = 0.f, a1 = 0.f;
#pragma unroll
            for (int q = 0; q < 32; ++q) {
                uint4 hv0 = *(const uint4*)&h16u[0][q * 4];
                uint4 hv1 = *(const uint4*)&h16u[1][q * 4];
                a0 = dot2_(wA[q * 4 + 0], hv0.x, a0);
                a0 = dot2_(wA[q * 4 + 1], hv0.y, a0);
                a0 = dot2_(wA[q * 4 + 2], hv0.z, a0);
                a0 = dot2_(wA[q * 4 + 3], hv0.w, a0);
                a1 = dot2_(wA[q * 4 + 0], hv1.x, a1);
                a1 = dot2_(wA[q * 4 + 1], hv1.y, a1);
                a1 = dot2_(wA[q * 4 + 2], hv1.z, a1);
                a1 = dot2_(wA[q * 4 + 3], hv1.w, a1);
            }
            P1[0][tid] = a0;
            P1[1][tid] = a1;
        }
        __syncthreads();

        // ---- elementwise 1 (waves 0,1) ----
        if (wid < 2) {
            float zr[4], rr[4], tmp[4];
            float4 pr = *(const float4*)&P1[row][4 * lane];
            float4 pz = *(const float4*)&P1[row][256 + 4 * lane];
            rr[0] = pr.x; rr[1] = pr.y; rr[2] = pr.z; rr[3] = pr.w;
            zr[0] = pz.x; zr[1] = pz.y; zr[2] = pz.z; zr[3] = pz.w;
            float hn = fmaxf(rnorm4(hreg), EPS_);
            // z gate
            mv_finish_reg(zr, hn);
            madd_reg(zr, uxp_z);
            {
                float4 bz = *(const float4*)&bias_s[2][4 * lane];
                tmp[0] = bz.x; tmp[1] = bz.y; tmp[2] = bz.z; tmp[3] = bz.w;
            }
            madd_reg(zr, tmp);
            lsig_reg(zr);
#pragma unroll
            for (int q = 0; q < 4; ++q) zv[q] = zr[q];
            // r gate
            mv_finish_reg(rr, hn);
            madd_reg(rr, uxp_r);
            {
                float4 br = *(const float4*)&bias_s[0][4 * lane];
                tmp[0] = br.x; tmp[1] = br.y; tmp[2] = br.z; tmp[3] = br.w;
            }
            madd_reg(rr, tmp);
            lsig_reg(rr);
            // rh -> packed f16
            float rh[4];
            pmul_reg(rr, hreg, rh, &rhn);
            c16u[row][2 * lane]     = packf16(rh[0], rh[1]);
            c16u[row][2 * lane + 1] = packf16(rh[2], rh[3]);
        }
        __syncthreads();

        // ---- phase2: rh @ W_hhh^T (dot2, k split in 2 halves) ----
        {
            float c0 = 0.f, c1 = 0.f;
#pragma unroll
            for (int q = 0; q < 16; ++q) {
                uint4 cv0 = *(const uint4*)&c16u[0][kb2 + q * 4];
                uint4 cv1 = *(const uint4*)&c16u[1][kb2 + q * 4];
                c0 = dot2_(wB[q * 4 + 0], cv0.x, c0);
                c0 = dot2_(wB[q * 4 + 1], cv0.y, c0);
                c0 = dot2_(wB[q * 4 + 2], cv0.z, c0);
                c0 = dot2_(wB[q * 4 + 3], cv0.w, c0);
                c1 = dot2_(wB[q * 4 + 0], cv1.x, c1);
                c1 = dot2_(wB[q * 4 + 1], cv1.y, c1);
                c1 = dot2_(wB[q * 4 + 2], cv1.z, c1);
                c1 = dot2_(wB[q * 4 + 3], cv1.w, c1);
            }
            P2[half][0][j2i] = c0;
            P2[half][1][j2i] = c1;
        }
        __syncthreads();

        // ---- elementwise 2 (waves 0,1): h update ----
        if (wid < 2) {
            float ht[4], tmp[4];
            float4 p0 = *(const float4*)&P2[0][row][4 * lane];
            float4 p1 = *(const float4*)&P2[1][row][4 * lane];
            ht[0] = p0.x + p1.x; ht[1] = p0.y + p1.y;
            ht[2] = p0.z + p1.z; ht[3] = p0.w + p1.w;
            mv_finish_reg(ht, rhn);
            madd_reg(ht, uxp_h);
            {
                float4 bh = *(const float4*)&bias_s[1][4 * lane];
                tmp[0] = bh.x; tmp[1] = bh.y; tmp[2] = bh.z; tmp[3] = bh.w;
            }
            madd_reg(ht, tmp);                 // ht = h_tilde
            float dl[4];
#pragma unroll
            for (int q = 0; q < 4; ++q) dl[q] = -hreg[q];
            madd_reg(dl, ht);                  // delta = mobius_add(-h, h_tilde)
            float dv[4];
            pmul_reg(zv, dl, dv, nullptr);     // z (*) delta
            madd_reg(hreg, dv);                // h = mobius_add(h, ...)
            float* orow = Hfull + ((size_t)(b0 + row) * T_ + t) * H_;
            *(float4*)&orow[4 * lane] = make_float4(hreg[0], hreg[1], hreg[2], hreg[3]);
            h16u[row][2 * lane]     = packf16(hreg[0], hreg[1]);
            h16u[row][2 * lane + 1] = packf16(hreg[2], hreg[3]);
        }
        __syncthreads();
    }
}

// logmap0 in place over (rows, 256)
__global__ __launch_bounds__(256) void k_logmap(float* __restrict__ Y) {
    int wid = threadIdx.x >> 6, lane = threadIdx.x & 63;
    int row = blockIdx.x * 4 + wid;
    float* p = Y + (size_t)row * H_;
    float v0 = p[lane], v1 = p[lane + 64], v2 = p[lane + 128], v3 = p[lane + 192];
    float ss = wred(v0 * v0 + v1 * v1 + v2 * v2 + v3 * v3);
    float n = fmaxf(sqrtf(fmaxf(ss, 1e-15f)), EPS_);
    float s = artanh_(n) / n;
    p[lane] = v0 * s; p[lane + 64] = v1 * s; p[lane + 128] = v2 * s; p[lane + 192] = v3 * s;
}

// score[b,t] = v . tanh(S1 + b1 + q[b]) + bv, masked
__global__ __launch_bounds__(256) void k_score(
    const float* __restrict__ S1, const float* __restrict__ q,
    const float* __restrict__ b1, const float* __restrict__ av,
    const float* __restrict__ abv, const int* __restrict__ len,
    float* __restrict__ sc)
{
    int wid = threadIdx.x >> 6, lane = threadIdx.x & 63;
    int row = blockIdx.x * 4 + wid;
    int b = row / T_, t = row - b * T_;
    const float* s1 = S1 + (size_t)row * H_;
    const float* qp = q + (size_t)b * H_;
    float part = 0.f;
#pragma unroll
    for (int qq = 0; qq < 4; ++qq) {
        int j = lane + 64 * qq;
        float u = tanhf(s1[j] + b1[j] + qp[j]);
        part = fmaf(u, av[j], part);
    }
    part = wred(part) + abv[0];
    if (t >= len[b]) part = -1e9f;
    if (lane == 0) sc[row] = part;
}

// per-b: softmax over T, ctx = sum w*full, span logits + softmax -> d_out
__global__ __launch_bounds__(256) void k_ctx(
    const float* __restrict__ sc, const float* __restrict__ full,
    const float* __restrict__ spw, const float* __restrict__ spb,
    float* __restrict__ ctx, float* __restrict__ outsp)
{
    int b = blockIdx.x, tid = threadIdx.x;
    __shared__ float w_s[T_];
    __shared__ float cs[H_];
    __shared__ float red[NSPAN];
    if (tid < T_) w_s[tid] = sc[b * T_ + tid];
    __syncthreads();
    if (tid == 0) {
        float mx = -1e30f;
        for (int t = 0; t < T_; ++t) mx = fmaxf(mx, w_s[t]);
        float sum = 0.f;
        for (int t = 0; t < T_; ++t) { float e = expf(w_s[t] - mx); w_s[t] = e; sum += e; }
        float inv = 1.f / sum;
        for (int t = 0; t < T_; ++t) w_s[t] *= inv;
    }
    __syncthreads();
    float c = 0.f;
    for (int t = 0; t < T_; ++t) c = fmaf(w_s[t], full[((size_t)b * T_ + t) * H_ + tid], c);
    ctx[(size_t)b * H_ + tid] = c;
    cs[tid] = c;
    __syncthreads();
    if (tid < NSPAN) {
        float lg = spb[tid];
        for (int j = 0; j < H_; ++j) lg = fmaf(spw[tid * H_ + j], cs[j], lg);
        red[tid] = lg;
    }
    __syncthreads();
    if (tid == 0) {
        float mx = red[0];
        for (int k2 = 1; k2 < NSPAN; ++k2) mx = fmaxf(mx, red[k2]);
        float sum = 0.f;
        for (int k2 = 0; k2 < NSPAN; ++k2) sum += expf(red[k2] - mx);
        float inv = 1.f / sum;
        for (int k2 = 0; k2 < NSPAN; ++k2) outsp[(size_t)b * NSPAN + k2] = expf(red[k2] - mx) * inv;
    }
}

// Euclidean GRU cell + fc_out softmax
__global__ __launch_bounds__(256) void k_dec_cell(
    const float* __restrict__ gi, const float* __restrict__ gh,
    float* __restrict__ h, const float* __restrict__ fow,
    const float* __restrict__ fob, float* __restrict__ outp, int t)
{
    int b = blockIdx.x, j = threadIdx.x;
    __shared__ float hs[H_];
    __shared__ float red[2];
    size_t gb = (size_t)b * 768;
    float r = sigm_(gi[gb + j] + gh[gb + j]);
    float z = sigm_(gi[gb + 256 + j] + gh[gb + 256 + j]);
    float n = tanhf(fmaf(r, gh[gb + 512 + j], gi[gb + 512 + j]));
    float hv = h[(size_t)b * H_ + j];
    float hnew = (1.f - z) * n + z * hv;
    h[(size_t)b * H_ + j] = hnew;
    hs[j] = hnew;
    __syncthreads();
    int wid = j >> 6, lane = j & 63;
    if (wid < 2) {
        float p = 0.f;
#pragma unroll
        for (int q = 0; q < 4; ++q) { int c = lane + 64 * q; p = fmaf(fow[wid * H_ + c], hs[c], p); }
        p = wred(p);
        if (lane == 0) red[wid] = p + fob[wid];
    }
    __syncthreads();
    if (j == 0) {
        float l0 = red[0], l1 = red[1];
        float mx = fmaxf(l0, l1);
        float e0 = expf(l0 - mx), e1 = expf(l1 - mx);
        float inv = 1.f / (e0 + e1);
        outp[(size_t)b * (NDAYS * OUTD) + t * OUTD + 0] = e0 * inv;
        outp[(size_t)b * (NDAYS * OUTD) + t * OUTD + 1] = e1 * inv;
    }
}

extern "C" void kernel_launch(void* const* d_in, const int* in_sizes, int n_in,
                              void* d_out, int out_size, void* d_ws, size_t ws_size,
                              hipStream_t stream)
{
    (void)in_sizes; (void)n_in; (void)out_size; (void)ws_size;
    const float* x        = (const float*)d_in[0];
    const int*   len      = (const int*)  d_in[1];
    const float* enc_w_ih = (const float*)d_in[2];
    const float* enc_w_hh = (const float*)d_in[3];
    const float* enc_bias = (const float*)d_in[4];
    const float* dec_w_ih = (const float*)d_in[5];
    const float* dec_w_hh = (const float*)d_in[6];
    const float* dec_b_ih = (const float*)d_in[7];
    const float* dec_b_hh = (const float*)d_in[8];
    const float* attn_w1  = (const float*)d_in[9];
    const float* attn_b1  = (const float*)d_in[10];
    const float* attn_w2  = (const float*)d_in[11];
    const float* attn_b2  = (const float*)d_in[12];
    const float* attn_v   = (const float*)d_in[13];
    const float* attn_bv  = (const float*)d_in[14];
    const float* fc_in_w  = (const float*)d_in[15];
    const float* fc_in_b  = (const float*)d_in[16];
    const float* fc_out_w = (const float*)d_in[17];
    const float* fc_out_b = (const float*)d_in[18];
    const float* span_w   = (const float*)d_in[19];
    const float* span_b   = (const float*)d_in[20];
    float* out = (float*)d_out;
    float* wsf = (float*)d_ws;

    const size_t ROWS = (size_t)B_ * T_;            // 38400
    float* UX    = wsf;                             // 38400*768
    float* Hfull = UX + ROWS * IN_;                 // 38400*256
    float* xs    = Hfull + ROWS * H_;               // 38400
    float* xnb   = xs + ROWS;                       // 38400
    float* WT    = xnb + ROWS;                      // 256*768 floats reserved (packed weights live here)
    float* bvv   = WT + 256 * 768;                  // 768
    float* qbuf  = bvv + 768;                       // 512*256
    float* scb   = qbuf + (size_t)B_ * H_;          // 38400
    float* ctx   = scb + ROWS;                      // 512*256 (doubles as decoder h)
    unsigned int* WPK = (unsigned int*)WT;          // 128*768 packed f16-pair uints
    // UX region reused after encoder/attention consume it:
    float* S1  = UX;
    float* gi  = UX;
    float* gh  = UX + (size_t)B_ * 768;
    float* inp = UX + 2 * (size_t)B_ * 768;

    k_bias<<<1, 256, 0, stream>>>(enc_bias, bvv);
    k_packw<<<128, 256, 0, stream>>>(enc_w_hh, WPK);
    k_row_scale<<<(unsigned)(ROWS / 4), 256, 0, stream>>>(x, xs, xnb);
    k_gemm_bt<<<dim3(IN_ / BN, (unsigned)(ROWS / BM)), 256, 0, stream>>>(x, IN_, enc_w_ih, nullptr, UX, IN_, IN_, 0);
    k_ux_scale<<<(unsigned)(ROWS * 3 / 4), 256, 0, stream>>>(UX, xs, xnb);
    k_encoder<<<B_ / 2, 512, 0, stream>>>(UX, WPK, bvv, Hfull);
    k_logmap<<<(unsigned)(ROWS / 4), 256, 0, stream>>>(Hfull);
    // q = hx @ w2^T + b2   (hx rows are the t=T-1 rows of logmapped Hfull, stride T*H)
    k_gemm_bt64<<<dim3(H_ / 64, B_ / 64), 256, 0, stream>>>(Hfull + (T_ - 1) * H_, T_ * H_, attn_w2, attn_b2, qbuf, H_, H_, 0);
    k_gemm_bt<<<dim3(H_ / BN, (unsigned)(ROWS / BM)), 256, 0, stream>>>(Hfull, H_, attn_w1, nullptr, S1, H_, H_, 0);
    k_score<<<(unsigned)(ROWS / 4), 256, 0, stream>>>(S1, qbuf, attn_b1, attn_v, attn_bv, len, scb);
    k_ctx<<<B_, 256, 0, stream>>>(scb, Hfull, span_w, span_b, ctx, out);
    hipMemsetAsync(inp, 0, (size_t)B_ * 768 * sizeof(float), stream);
    for (int t = 0; t < NDAYS; ++t) {
        k_gemm_bt64<<<dim3(768 / 64, B_ / 64), 256, 0, stream>>>(inp, 768, dec_w_ih, dec_b_ih, gi, 768, 768, 0);
        k_gemm_bt64<<<dim3(768 / 64, B_ / 64), 256, 0, stream>>>(ctx, H_, dec_w_hh, dec_b_hh, gh, 768, H_, 0);
        k_dec_cell<<<B_, 256, 0, stream>>>(gi, gh, ctx, fc_out_w, fc_out_b, out + B_ * NSPAN, t);
        if (t + 1 < NDAYS)
            k_gemm_bt64<<<dim3(768 / 64, B_ / 64), 256, 0, stream>>>(ctx, H_, fc_in_w, fc_in_b, inp, 768, H_, 1);
    }
}